// Round 1
// baseline (247.380 us; speedup 1.0000x reference)
//
#include <hip/hip_runtime.h>
#include <hip/hip_bf16.h>
#include <math.h>

// Problem constants
#define B_   16
#define D_   512
#define T_   2048
#define K_   8
#define C_   1024
#define CH_  64
#define NEL_ (B_ * D_ * T_)        // 16777216
#define QOFF 16777216              // out: [quantized | commit | ppl[8]]

// ws layout
#define WS_HCN   0                          // float[K*C]   32 KB (0.5*||c||^2)
#define WS_CNT   32768                      // int[K*C]     32 KB
#define WS_SSE   65536                      // double       8 B
#define WS_CBS   66048                      // swizzled bf16 (hi only) image, 8192 rows * 128 B = 1 MB
// image: row r (= k*1024+c) at WS_CBS + r*128; 16B group s (s=0..7, ch 8s..8s+7,
// negated bf16) stored at ((s ^ (r & 7)) * 16).

typedef __attribute__((ext_vector_type(8))) short   short8;
typedef __attribute__((ext_vector_type(8))) __bf16  bf16x8;
typedef __attribute__((ext_vector_type(4))) float   f32x4;
typedef __attribute__((ext_vector_type(4))) int     i32x4;

__device__ __forceinline__ unsigned short f2bf_rne(float f) {
    unsigned u = __builtin_bit_cast(unsigned, f);
    u = u + 0x7FFFu + ((u >> 16) & 1u);
    return (unsigned short)(u >> 16);
}

__device__ __forceinline__ void gload_lds16(const void* gsrc, void* ldst) {
    __builtin_amdgcn_global_load_lds(
        (const __attribute__((address_space(1))) unsigned int*)gsrc,
        (__attribute__((address_space(3))) unsigned int*)ldst,
        16, 0, 0);
}

// ---------------------------------------------------------------------------
// Prep: swizzled bf16 (hi-only) image of (-c) + 0.5*||c||^2.
// One thread per 16B group: g = row*8 + s. 65536 threads.
// Also zero-inits counts + sse (replaces the hipMemsetAsync dispatch).
// ---------------------------------------------------------------------------
__global__ void vq_prep(const float* __restrict__ cb,
                        unsigned char* __restrict__ cbS,
                        float* __restrict__ hcn,
                        int* __restrict__ counts,
                        double* __restrict__ sse) {
    int g   = blockIdx.x * 256 + threadIdx.x;
    if (g < K_ * C_) counts[g] = 0;
    if (g == 0) *sse = 0.0;

    int row = g >> 3;
    int s8  = g & 7;
    const float* src = cb + (size_t)row * CH_;

    short8 val;
#pragma unroll
    for (int j = 0; j < 8; ++j)
        val[j] = (short)f2bf_rne(-src[s8 * 8 + j]);
    *(short8*)(cbS + (size_t)row * 128 + ((s8 ^ (row & 7)) * 16)) = val;

    if (s8 == 0) {
        float s = 0.f;
#pragma unroll 8
        for (int ch = 0; ch < CH_; ++ch) {
            float v = src[ch];
            s = fmaf(v, v, s);
        }
        hcn[row] = 0.5f * s;
    }
}

// ---------------------------------------------------------------------------
// Main. Block = 512 (8 waves); wave owns 32 t's (2 t-tiles) of one (b,k).
// Grid = 1024 = 4 blocks/CU at 37.9 KB LDS -> 32 waves/CU (was 16).
// Staging: swizzled hi-only image, global_load_lds 16B, double buffer.
// Argmin: per-slot strict-< value/index tracking, lexicographic merges so the
// 4 q-lanes converge bitwise on idx (R6/R8-proven constructs, unchanged).
// Output: idx published to LDS, then each wave stores 8 channel rows as
// fully-coalesced 1KB dwordx4 row-stores (kills partial-line write RMW).
// ---------------------------------------------------------------------------
#define LDSBUF 16384

__global__ __launch_bounds__(512, 8) void vq_main(
    const float* __restrict__ x,
    const float* __restrict__ cb,
    const unsigned char* __restrict__ cbS,
    const float* __restrict__ hcn,
    float* __restrict__ out,
    int* __restrict__ counts,
    double* __restrict__ sse)
{
    __shared__ __align__(16) unsigned char lds[2 * LDSBUF + 4096 + 1024];
    float* hcnS = (float*)(lds + 2 * LDSBUF);
    int*   idxS = (int*)(lds + 2 * LDSBUF + 4096);

    const int tid  = threadIdx.x;
    const int lane = tid & 63;
    const int wave = tid >> 6;          // 0..7
    const int ln   = lane & 15;
    const int q    = lane >> 4;
    const int q4   = q * 4;

    const int bid = blockIdx.x;
    const int tc  = bid & 7;            // 8 t-chunks of 256
    const int k   = (bid >> 3) & 7;
    const int b   = bid >> 6;
    const int t0  = tc * 256;           // block's t base
    const int tw  = t0 + wave * 32;     // wave's t base

    // ---- B fragments (queries) + ||x||^2 per query ----
    short8 bh[2][2];    // [tt][kstep]
    float  xn[2];       // ||x_t||^2 for t = tw + tt*16 + ln (all lanes)
#pragma unroll
    for (int tt = 0; tt < 2; ++tt) {
        int t = tw + tt * 16 + ln;
        float pn = 0.f;
#pragma unroll
        for (int ks = 0; ks < 2; ++ks) {
            const float* xp = x + ((size_t)(b * D_ + k * CH_ + ks * 32 + q * 8)) * T_ + t;
            short8 sh;
#pragma unroll
            for (int j = 0; j < 8; ++j) {
                float v = xp[(size_t)j * T_];
                pn = fmaf(v, v, pn);
                sh[j] = (short)f2bf_rne(v);
            }
            bh[tt][ks] = sh;
        }
        pn += __shfl_xor(pn, 16);       // sum the 4 q-lane partials
        pn += __shfl_xor(pn, 32);
        xn[tt] = pn;
    }

    const unsigned char* cbS_k = cbS + (size_t)k * C_ * 128;
    const float*         hcn_k = hcn + k * C_;

    // Stage hcn (4 KB) once via plain LDS writes (visible at first barrier).
    for (int i = tid; i < C_; i += 512) hcnS[i] = hcn_k[i];

    // Stage chunk 0 (128 codes, 16 KB) into buf0: each wave 2 x 1 KB async.
    {
        const unsigned char* src = cbS_k + wave * 2048 + lane * 16;
        unsigned char* dst = lds + wave * 2048;
#pragma unroll
        for (int i = 0; i < 2; ++i)
            gload_lds16(src + i * 1024, dst + i * 1024);
    }

    // Per-slot running minima. Slot (tt, r): code = j*16 + q*4 + r.
    float md[2][4];
    int   mj[2][4];
#pragma unroll
    for (int tt = 0; tt < 2; ++tt)
#pragma unroll
        for (int r = 0; r < 4; ++r) { md[tt][r] = INFINITY; mj[tt][r] = 0; }

    for (int chunk = 0; chunk < 8; ++chunk) {
        __syncthreads();   // drains this chunk's async loads (+hcnS on iter 0)

        if (chunk < 7) {   // prefetch next chunk into the other buffer
            const unsigned char* src =
                cbS_k + (size_t)(chunk + 1) * 16384 + wave * 2048 + lane * 16;
            unsigned char* dst = lds + ((chunk + 1) & 1) * LDSBUF + wave * 2048;
#pragma unroll
            for (int i = 0; i < 2; ++i)
                gload_lds16(src + i * 1024, dst + i * 1024);
        }

        const unsigned char* buf = lds + (chunk & 1) * LDSBUF;
#pragma unroll
        for (int sub = 0; sub < 8; ++sub) {
            const unsigned char* rowb = buf + (sub * 16 + ln) * 128;
            f32x4 h4 = *(const f32x4*)(hcnS + chunk * 128 + sub * 16 + q4);
            f32x4 a[2];
            a[0] = h4;
            a[1] = h4;
#pragma unroll
            for (int ks = 0; ks < 2; ++ks) {
                int cidx = ((ks * 4 + q) ^ (ln & 7)) * 16;
                bf16x8 ah = __builtin_bit_cast(bf16x8, *(const short8*)(rowb + cidx));
#pragma unroll
                for (int tt = 0; tt < 2; ++tt)
                    a[tt] = __builtin_amdgcn_mfma_f32_16x16x32_bf16(
                        ah, __builtin_bit_cast(bf16x8, bh[tt][ks]), a[tt], 0, 0, 0);
            }
            const int j = chunk * 8 + sub;
#pragma unroll
            for (int tt = 0; tt < 2; ++tt) {
#pragma unroll
                for (int r = 0; r < 4; ++r) {
                    bool lt = a[tt][r] < md[tt][r];
                    md[tt][r] = lt ? a[tt][r] : md[tt][r];
                    mj[tt][r] = lt ? j : mj[tt][r];
                }
            }
        }
    }

    // ---- Epilogue A: top-1 consensus + SSE + counts + idx publish ----
    double waveSse = 0.0;

#pragma unroll
    for (int tt = 0; tt < 2; ++tt) {
        // Fold 4 slots -> in-lane top-1, lexicographic (value, code).
        float d1 = md[tt][0];
        int   c1 = mj[tt][0] * 16 + q4;
#pragma unroll
        for (int r = 1; r < 4; ++r) {
            float v  = md[tt][r];
            int   cv = mj[tt][r] * 16 + q4 + r;
            bool w = (v < d1) || (v == d1 && cv < c1);
            d1 = w ? v : d1;
            c1 = w ? cv : c1;
        }
        // Cross-lane top-1 merge over q (xor 16, 32), lexicographic ->
        // all 4 q-lanes converge bitwise on the same (d1, c1).
#pragma unroll
        for (int off = 16; off <= 32; off <<= 1) {
            float ov = __shfl_xor(d1, off);
            int   oc = __shfl_xor(c1, off);
            bool w = (ov < d1) || (ov == d1 && oc < c1);
            d1 = w ? ov : d1;
            c1 = w ? oc : c1;
        }

        if (q == 0) {                        // one vote per query
            // ||x - c||^2 = ||x||^2 + 2*(0.5||c||^2 - x.c) = xn + 2*score
            waveSse += (double)(xn[tt] + 2.0f * d1);
            atomicAdd(&counts[k * C_ + c1], 1);
            idxS[wave * 32 + tt * 16 + ln] = c1;
        }
    }

    // One fp64 atomic per wave.
    for (int off = 32; off > 0; off >>= 1) waveSse += __shfl_down(waveSse, off);
    if (lane == 0) atomicAdd(sse, waveSse);

    __syncthreads();   // idx table visible to all waves

    // ---- Epilogue B: coalesced quantized write ----
    // Wave owns 8 channel rows (ch = wave*8 + rr); lane l covers t = t0+4l..+3.
    // Gather the 4 needed codebook rows as float4 pairs (L2-hot), register-
    // transpose, store 1KB-contiguous dwordx4 rows.
    const float* cb_k = cb + (size_t)k * C_ * CH_;
    i32x4 idx4 = *(const i32x4*)(idxS + 4 * lane);

    float vals[4][8];
#pragma unroll
    for (int m = 0; m < 4; ++m) {
        const float* rp = cb_k + (size_t)idx4[m] * CH_ + wave * 8;
        f32x4 a0 = *(const f32x4*)rp;
        f32x4 a1 = *(const f32x4*)(rp + 4);
#pragma unroll
        for (int jj = 0; jj < 4; ++jj) {
            vals[m][jj]     = a0[jj];
            vals[m][jj + 4] = a1[jj];
        }
    }
#pragma unroll
    for (int rr = 0; rr < 8; ++rr) {
        f32x4 v = { vals[0][rr], vals[1][rr], vals[2][rr], vals[3][rr] };
        *(f32x4*)(out + ((size_t)(b * D_ + k * CH_ + wave * 8 + rr)) * T_
                      + t0 + 4 * lane) = v;
    }
}

// ---------------------------------------------------------------------------
// Finalize: one block per k -> perplexity; block 0 also writes commit loss.
// ---------------------------------------------------------------------------
__global__ void vq_final(const int* __restrict__ counts,
                         const double* __restrict__ sse,
                         float* __restrict__ out) {
    __shared__ double part[4];
    const int tid = threadIdx.x;
    const int k   = blockIdx.x;
    double local = 0.0;
    for (int j = tid; j < C_; j += 256) {
        double p = (double)counts[k * C_ + j] * (1.0 / (double)(B_ * T_));
        local += -p * log(p + 1e-8);
    }
    for (int off = 32; off > 0; off >>= 1) local += __shfl_down(local, off);
    if ((tid & 63) == 0) part[tid >> 6] = local;
    __syncthreads();
    if (tid == 0) {
        double sum = part[0] + part[1] + part[2] + part[3];
        out[QOFF + 1 + k] = (float)exp(sum);
        if (k == 0)
            out[QOFF] = (float)(1.25 * (*sse) / (double)NEL_);
    }
}

// ---------------------------------------------------------------------------
extern "C" void kernel_launch(void* const* d_in, const int* in_sizes, int n_in,
                              void* d_out, int out_size, void* d_ws, size_t ws_size,
                              hipStream_t stream) {
    const float* x  = (const float*)d_in[0];
    const float* cb = (const float*)d_in[1];
    float* out = (float*)d_out;

    float*         hcn    = (float*)((char*)d_ws + WS_HCN);
    int*           counts = (int*)((char*)d_ws + WS_CNT);
    double*        sse    = (double*)((char*)d_ws + WS_SSE);
    unsigned char* cbS    = (unsigned char*)((char*)d_ws + WS_CBS);

    vq_prep<<<(K_ * C_ * 8) / 256, 256, 0, stream>>>(cb, cbS, hcn, counts, sse);
    vq_main<<<B_ * K_ * (T_ / 256), 512, 0, stream>>>(x, cb, cbS, hcn,
                                                      out, counts, sse);
    vq_final<<<K_, 256, 0, stream>>>(counts, sse, out);
}

// Round 2
// 239.192 us; speedup vs baseline: 1.0342x; 1.0342x over previous
//
#include <hip/hip_runtime.h>
#include <hip/hip_bf16.h>
#include <math.h>

// Problem constants
#define B_   16
#define D_   512
#define T_   2048
#define K_   8
#define C_   1024
#define CH_  64
#define NEL_ (B_ * D_ * T_)        // 16777216
#define QOFF 16777216              // out: [quantized | commit | ppl[8]]

// ws layout
#define WS_HCN   0                          // float[K*C]   32 KB (0.5*||c||^2)
#define WS_CNT   32768                      // int[K*C]     32 KB
#define WS_SSE   65536                      // double       8 B
#define WS_CBS   66048                      // swizzled bf16 (hi only) image, 8192 rows * 128 B = 1 MB
// image: row r (= k*1024+c) at WS_CBS + r*128; 16B group s (s=0..7, ch 8s..8s+7,
// negated bf16) stored at ((s ^ (r & 7)) * 16).

typedef __attribute__((ext_vector_type(8))) short   short8;
typedef __attribute__((ext_vector_type(8))) __bf16  bf16x8;
typedef __attribute__((ext_vector_type(4))) float   f32x4;

__device__ __forceinline__ unsigned short f2bf_rne(float f) {
    unsigned u = __builtin_bit_cast(unsigned, f);
    u = u + 0x7FFFu + ((u >> 16) & 1u);
    return (unsigned short)(u >> 16);
}

__device__ __forceinline__ void gload_lds16(const void* gsrc, void* ldst) {
    __builtin_amdgcn_global_load_lds(
        (const __attribute__((address_space(1))) unsigned int*)gsrc,
        (__attribute__((address_space(3))) unsigned int*)ldst,
        16, 0, 0);
}

// ---------------------------------------------------------------------------
// Prep: swizzled bf16 (hi-only) image of (-c) + 0.5*||c||^2.
// One thread per 16B group: g = row*8 + s. 65536 threads.
// Also zero-inits counts + sse (replaces the hipMemsetAsync dispatch).
// ---------------------------------------------------------------------------
__global__ void vq_prep(const float* __restrict__ cb,
                        unsigned char* __restrict__ cbS,
                        float* __restrict__ hcn,
                        int* __restrict__ counts,
                        double* __restrict__ sse) {
    int g   = blockIdx.x * 256 + threadIdx.x;
    if (g < K_ * C_) counts[g] = 0;
    if (g == 0) *sse = 0.0;

    int row = g >> 3;
    int s8  = g & 7;
    const float* src = cb + (size_t)row * CH_;

    short8 val;
#pragma unroll
    for (int j = 0; j < 8; ++j)
        val[j] = (short)f2bf_rne(-src[s8 * 8 + j]);
    *(short8*)(cbS + (size_t)row * 128 + ((s8 ^ (row & 7)) * 16)) = val;

    if (s8 == 0) {
        float s = 0.f;
#pragma unroll 8
        for (int ch = 0; ch < CH_; ++ch) {
            float v = src[ch];
            s = fmaf(v, v, s);
        }
        hcn[row] = 0.5f * s;
    }
}

// ---------------------------------------------------------------------------
// Main. Block = 256 (4 waves); wave owns 32 t's (2 t-tiles) of one (b,k).
// Grid = 2048 = exactly 8 blocks/CU at 16.9 KB LDS -> 32 waves/CU,
// REQUIRES <=64 VGPR: state slimmed (2 t-tiles, mj byte-packed into one u32
// per tile, hcn read from global/L1 instead of LDS) so nothing spills.
// R0/R1 post-mortem: ~100 MB of WRITE_SIZE was scratch spill writeback, not
// output RMW — despilling is the lever.
// Staging: swizzled hi-only image, global_load_lds 16B, 64-code chunks,
// double buffer. Argmin: per-slot strict-< value/index tracking, all merges
// lexicographic (value, code) so the 4 q-lanes converge bitwise on idx.
// Output: idx published to LDS, then fully-coalesced float2 row stores.
// ---------------------------------------------------------------------------
#define LDSBUF 8192

__global__ __launch_bounds__(256, 8) void vq_main(
    const float* __restrict__ x,
    const float* __restrict__ cb,
    const unsigned char* __restrict__ cbS,
    const float* __restrict__ hcn,
    float* __restrict__ out,
    int* __restrict__ counts,
    double* __restrict__ sse)
{
    __shared__ __align__(16) unsigned char lds[2 * LDSBUF + 512];
    int* idxS = (int*)(lds + 2 * LDSBUF);

    const int tid  = threadIdx.x;
    const int lane = tid & 63;
    const int wave = tid >> 6;          // 0..3
    const int ln   = lane & 15;
    const int q    = lane >> 4;
    const int q4   = q * 4;

    const int bid = blockIdx.x;
    const int tc  = bid & 15;           // 16 t-chunks of 128
    const int k   = (bid >> 4) & 7;
    const int b   = bid >> 7;
    const int t0  = tc * 128;           // block's t base
    const int tw  = t0 + wave * 32;     // wave's t base

    // ---- B fragments (queries) + ||x||^2 per query ----
    short8 bh[2][2];    // [tt][kstep]
    float  xn[2];       // ||x_t||^2 for t = tw + tt*16 + ln (all lanes)
#pragma unroll
    for (int tt = 0; tt < 2; ++tt) {
        int t = tw + tt * 16 + ln;
        float pn = 0.f;
#pragma unroll
        for (int ks = 0; ks < 2; ++ks) {
            const float* xp = x + ((size_t)(b * D_ + k * CH_ + ks * 32 + q * 8)) * T_ + t;
            short8 sh;
#pragma unroll
            for (int j = 0; j < 8; ++j) {
                float v = xp[(size_t)j * T_];
                pn = fmaf(v, v, pn);
                sh[j] = (short)f2bf_rne(v);
            }
            bh[tt][ks] = sh;
        }
        pn += __shfl_xor(pn, 16);       // sum the 4 q-lane partials
        pn += __shfl_xor(pn, 32);
        xn[tt] = pn;
    }

    const unsigned char* cbS_k = cbS + (size_t)k * C_ * 128;
    const float*         hcn_k = hcn + k * C_;

    // Stage chunk 0 (64 codes, 8 KB) into buf0: 256 threads x 2 x 16 B async.
    {
        const unsigned char* src = cbS_k + tid * 16;
        unsigned char* dst = lds + tid * 16;
        gload_lds16(src,        dst);
        gload_lds16(src + 4096, dst + 4096);
    }

    // Per-slot running minima. Slot (tt, r): code = j*16 + q*4 + r,
    // j = chunk*4 + sub in [0,64) -> mj byte-packed (4 x 8-bit) per tt.
    float    md[2][4];
    unsigned mjp[2];
#pragma unroll
    for (int tt = 0; tt < 2; ++tt) {
        mjp[tt] = 0u;
#pragma unroll
        for (int r = 0; r < 4; ++r) md[tt][r] = INFINITY;
    }

    for (int chunk = 0; chunk < 16; ++chunk) {
        __syncthreads();   // drains this chunk's async loads

        if (chunk < 15) {  // prefetch next chunk into the other buffer
            const unsigned char* src = cbS_k + (size_t)(chunk + 1) * 8192 + tid * 16;
            unsigned char* dst = lds + ((chunk + 1) & 1) * LDSBUF + tid * 16;
            gload_lds16(src,        dst);
            gload_lds16(src + 4096, dst + 4096);
        }

        const unsigned char* buf = lds + (chunk & 1) * LDSBUF;
#pragma unroll
        for (int sub = 0; sub < 4; ++sub) {
            const unsigned char* rowb = buf + (sub * 16 + ln) * 128;
            // h = 0.5||c||^2 for codes j*16+q4..+3: 4 distinct 16B lines per
            // wave-instr, L1-broadcast (hcn is 32 KB, L2-resident).
            f32x4 h4 = *(const f32x4*)(hcn_k + chunk * 64 + sub * 16 + q4);
            f32x4 a[2];
            a[0] = h4;
            a[1] = h4;
#pragma unroll
            for (int ks = 0; ks < 2; ++ks) {
                int cidx = ((ks * 4 + q) ^ (ln & 7)) * 16;
                bf16x8 ah = __builtin_bit_cast(bf16x8, *(const short8*)(rowb + cidx));
#pragma unroll
                for (int tt = 0; tt < 2; ++tt)
                    a[tt] = __builtin_amdgcn_mfma_f32_16x16x32_bf16(
                        ah, __builtin_bit_cast(bf16x8, bh[tt][ks]), a[tt], 0, 0, 0);
            }
            const unsigned j = (unsigned)(chunk * 4 + sub);
#pragma unroll
            for (int tt = 0; tt < 2; ++tt) {
#pragma unroll
                for (int r = 0; r < 4; ++r) {
                    bool lt = a[tt][r] < md[tt][r];
                    md[tt][r] = lt ? a[tt][r] : md[tt][r];
                    unsigned upd = (mjp[tt] & ~(0xFFu << (8 * r))) | (j << (8 * r));
                    mjp[tt] = lt ? upd : mjp[tt];
                }
            }
        }
    }

    // ---- Epilogue A: top-1 consensus + SSE + counts + idx publish ----
    double waveSse = 0.0;

#pragma unroll
    for (int tt = 0; tt < 2; ++tt) {
        // Fold 4 slots -> in-lane top-1, lexicographic (value, code).
        float d1 = md[tt][0];
        int   c1 = (int)(mjp[tt] & 0xFFu) * 16 + q4;
#pragma unroll
        for (int r = 1; r < 4; ++r) {
            float v  = md[tt][r];
            int   cv = (int)((mjp[tt] >> (8 * r)) & 0xFFu) * 16 + q4 + r;
            bool w = (v < d1) || (v == d1 && cv < c1);
            d1 = w ? v : d1;
            c1 = w ? cv : c1;
        }
        // Cross-lane top-1 merge over q (xor 16, 32), lexicographic ->
        // all 4 q-lanes converge bitwise on the same (d1, c1).
#pragma unroll
        for (int off = 16; off <= 32; off <<= 1) {
            float ov = __shfl_xor(d1, off);
            int   oc = __shfl_xor(c1, off);
            bool w = (ov < d1) || (ov == d1 && oc < c1);
            d1 = w ? ov : d1;
            c1 = w ? oc : c1;
        }

        if (q == 0) {                        // one vote per query
            // ||x - c||^2 = ||x||^2 + 2*(0.5||c||^2 - x.c) = xn + 2*score
            waveSse += (double)(xn[tt] + 2.0f * d1);
            atomicAdd(&counts[k * C_ + c1], 1);
            idxS[wave * 32 + tt * 16 + ln] = c1;   // idxS[i] = idx for t0+i
        }
    }

    // One fp64 atomic per wave.
    for (int off = 32; off > 0; off >>= 1) waveSse += __shfl_down(waveSse, off);
    if (lane == 0) atomicAdd(sse, waveSse);

    __syncthreads();   // idx table visible to all waves

    // ---- Epilogue B: coalesced quantized write ----
    // Wave owns 16 channel rows (ch = wave*16 + cc); lane l covers t = t0+2l,
    // t0+2l+1. Gather the lane's two codebook row-slices (4 x f32x4 each,
    // L2-hot), emit float2 stores: 512 B fully-contiguous per wave-instr.
    const float* cb_k = cb + (size_t)k * C_ * CH_;
    const int i0 = idxS[2 * lane];
    const int i1 = idxS[2 * lane + 1];
    const float* r0 = cb_k + (size_t)i0 * CH_ + wave * 16;
    const float* r1 = cb_k + (size_t)i1 * CH_ + wave * 16;
#pragma unroll
    for (int p = 0; p < 4; ++p) {
        f32x4 a0 = *(const f32x4*)(r0 + 4 * p);
        f32x4 a1 = *(const f32x4*)(r1 + 4 * p);
#pragma unroll
        for (int jj = 0; jj < 4; ++jj) {
            int ch = wave * 16 + 4 * p + jj;
            float2 v = make_float2(a0[jj], a1[jj]);
            *(float2*)(out + ((size_t)(b * D_ + k * CH_ + ch)) * T_
                           + t0 + 2 * lane) = v;
        }
    }
}

// ---------------------------------------------------------------------------
// Finalize: one block per k -> perplexity; block 0 also writes commit loss.
// ---------------------------------------------------------------------------
__global__ void vq_final(const int* __restrict__ counts,
                         const double* __restrict__ sse,
                         float* __restrict__ out) {
    __shared__ double part[4];
    const int tid = threadIdx.x;
    const int k   = blockIdx.x;
    double local = 0.0;
    for (int j = tid; j < C_; j += 256) {
        double p = (double)counts[k * C_ + j] * (1.0 / (double)(B_ * T_));
        local += -p * log(p + 1e-8);
    }
    for (int off = 32; off > 0; off >>= 1) local += __shfl_down(local, off);
    if ((tid & 63) == 0) part[tid >> 6] = local;
    __syncthreads();
    if (tid == 0) {
        double sum = part[0] + part[1] + part[2] + part[3];
        out[QOFF + 1 + k] = (float)exp(sum);
        if (k == 0)
            out[QOFF] = (float)(1.25 * (*sse) / (double)NEL_);
    }
}

// ---------------------------------------------------------------------------
extern "C" void kernel_launch(void* const* d_in, const int* in_sizes, int n_in,
                              void* d_out, int out_size, void* d_ws, size_t ws_size,
                              hipStream_t stream) {
    const float* x  = (const float*)d_in[0];
    const float* cb = (const float*)d_in[1];
    float* out = (float*)d_out;

    float*         hcn    = (float*)((char*)d_ws + WS_HCN);
    int*           counts = (int*)((char*)d_ws + WS_CNT);
    double*        sse    = (double*)((char*)d_ws + WS_SSE);
    unsigned char* cbS    = (unsigned char*)((char*)d_ws + WS_CBS);

    vq_prep<<<(K_ * C_ * 8) / 256, 256, 0, stream>>>(cb, cbS, hcn, counts, sse);
    vq_main<<<B_ * K_ * (T_ / 128), 256, 0, stream>>>(x, cb, cbS, hcn,
                                                      out, counts, sse);
    vq_final<<<K_, 256, 0, stream>>>(counts, sse, out);
}

// Round 7
// 204.442 us; speedup vs baseline: 1.2100x; 1.1700x over previous
//
#include <hip/hip_runtime.h>
#include <hip/hip_bf16.h>
#include <math.h>

// Problem constants
#define B_   16
#define D_   512
#define T_   2048
#define K_   8
#define C_   1024
#define CH_  64
#define NEL_ (B_ * D_ * T_)        // 16777216
#define QOFF 16777216              // out: [quantized | commit | ppl[8]]

// ws layout
#define WS_HCN   0                          // float[K*C]   32 KB (0.5*||c||^2)
#define WS_CNT   32768                      // int[K*C]     32 KB
#define WS_SSE   65536                      // double       8 B
#define WS_CBS   66048                      // swizzled bf16 (hi only) image, 8192 rows * 128 B = 1 MB
// image: row r (= k*1024+c) at WS_CBS + r*128; 16B group s (s=0..7, ch 8s..8s+7,
// negated bf16) stored at ((s ^ (r & 7)) * 16).

typedef __attribute__((ext_vector_type(8))) short   short8;
typedef __attribute__((ext_vector_type(8))) __bf16  bf16x8;
typedef __attribute__((ext_vector_type(4))) float   f32x4;
typedef __attribute__((ext_vector_type(4))) int     i32x4;

__device__ __forceinline__ unsigned short f2bf_rne(float f) {
    unsigned u = __builtin_bit_cast(unsigned, f);
    u = u + 0x7FFFu + ((u >> 16) & 1u);
    return (unsigned short)(u >> 16);
}

__device__ __forceinline__ void gload_lds16(const void* gsrc, void* ldst) {
    __builtin_amdgcn_global_load_lds(
        (const __attribute__((address_space(1))) unsigned int*)gsrc,
        (__attribute__((address_space(3))) unsigned int*)ldst,
        16, 0, 0);
}

// ---------------------------------------------------------------------------
// Prep (R0/R2-proven): swizzled bf16 (hi-only) image of (-c) + 0.5*||c||^2,
// plus counts/sse zero-init. One thread per 16B group. 65536 threads.
// ---------------------------------------------------------------------------
__global__ void vq_prep(const float* __restrict__ cb,
                        unsigned char* __restrict__ cbS,
                        float* __restrict__ hcn,
                        int* __restrict__ counts,
                        double* __restrict__ sse) {
    int g   = blockIdx.x * 256 + threadIdx.x;
    if (g < K_ * C_) counts[g] = 0;
    if (g == 0) *sse = 0.0;

    int row = g >> 3;
    int s8  = g & 7;
    const float* src = cb + (size_t)row * CH_;

    short8 val;
#pragma unroll
    for (int j = 0; j < 8; ++j)
        val[j] = (short)f2bf_rne(-src[s8 * 8 + j]);
    *(short8*)(cbS + (size_t)row * 128 + ((s8 ^ (row & 7)) * 16)) = val;

    if (s8 == 0) {
        float s = 0.f;
#pragma unroll 8
        for (int ch = 0; ch < CH_; ++ch) {
            float v = src[ch];
            s = fmaf(v, v, s);
        }
        hcn[row] = 0.5f * s;
    }
}

// ---------------------------------------------------------------------------
// Main — R0's exact geometry (the session's best PASSING kernel, 125 µs)
// with R0's two measured wastes removed via R2-proven constructs only.
// R3-R6 post-mortem: every config with LDS >= 64 KiB silently never
// launched in this harness (ppl=exp(0) signature, clean-zero outputs);
// R7 stays at 37888 B = R1's exact proven LDS_Block_Size.
//
// Block = 256 (4 waves), wave owns 64 t (4 t-tiles) of one (b,k).
// Grid = 1024 = 4 blocks/CU -> 16 waves/CU.
// Staging: swizzled hi-only image, global_load_lds 16B, 128-code chunks,
// double buffer, 8 drains/block (R0-proven).
// Argmin: per-slot strict-< value tracking (R0-proven) with mj BYTE-PACKED
// into one u32 per t-tile (R2-proven, j = chunk*8+sub < 64 fits 8 bits):
// -12 VGPRs vs R0 -> despill (R0 spilled ~30 MB scratch at 64 VGPRs).
// __launch_bounds__(256, 2) relaxes the VGPR cap to avoid R1's forced-spill
// failure mode; occupancy stays LDS-bound at 4 blocks/CU.
// Epilogue: R2-proven idxS publish + coalesced full-line out-writes
// (R0's 64B half-line segments caused ~67 MB of RMW write amplification).
// All merges lexicographic (value, code) -> bitwise q-lane convergence;
// idx choices bit-identical to R0's passing run.
// ---------------------------------------------------------------------------
#define LDSBUF 16384

__global__ __launch_bounds__(256, 2) void vq_main(
    const float* __restrict__ x,
    const float* __restrict__ cb,
    const unsigned char* __restrict__ cbS,
    const float* __restrict__ hcn,
    float* __restrict__ out,
    int* __restrict__ counts,
    double* __restrict__ sse)
{
    __shared__ __align__(16) unsigned char lds[2 * LDSBUF + 4096 + 1024];
    float* hcnS = (float*)(lds + 2 * LDSBUF);
    int*   idxS = (int*)(lds + 2 * LDSBUF + 4096);

    const int tid  = threadIdx.x;
    const int lane = tid & 63;
    const int wave = tid >> 6;          // 0..3
    const int ln   = lane & 15;
    const int q    = lane >> 4;
    const int q4   = q * 4;

    const int bid = blockIdx.x;
    const int tc  = bid & 7;            // 8 t-chunks of 256
    const int k   = (bid >> 3) & 7;
    const int b   = bid >> 6;
    const int t0b = tc * 256;           // block's t base
    const int tw  = t0b + wave * 64;    // wave's t base

    // ---- B fragments (queries) + ||x||^2 per query (R0 verbatim) ----
    short8 bh[4][2];    // [tt][kstep]
    float  xn[4];       // ||x_t||^2 for t = tw + tt*16 + ln (all lanes)
#pragma unroll
    for (int tt = 0; tt < 4; ++tt) {
        int t = tw + tt * 16 + ln;
        float pn = 0.f;
#pragma unroll
        for (int ks = 0; ks < 2; ++ks) {
            const float* xp = x + ((size_t)(b * D_ + k * CH_ + ks * 32 + q * 8)) * T_ + t;
            short8 sh;
#pragma unroll
            for (int j = 0; j < 8; ++j) {
                float v = xp[(size_t)j * T_];
                pn = fmaf(v, v, pn);
                sh[j] = (short)f2bf_rne(v);
            }
            bh[tt][ks] = sh;
        }
        pn += __shfl_xor(pn, 16);       // sum the 4 q-lane partials
        pn += __shfl_xor(pn, 32);
        xn[tt] = pn;
    }

    const unsigned char* cbS_k = cbS + (size_t)k * C_ * 128;
    const float*         hcn_k = hcn + k * C_;

    // Stage hcn (4 KB) once via plain LDS writes (visible at first barrier).
    for (int i = tid; i < C_; i += 256) hcnS[i] = hcn_k[i];

    // Stage chunk 0 (128 codes, 16 KB) into buf0: each wave 4 x 1 KB async.
    {
        const unsigned char* src = cbS_k + wave * 4096 + lane * 16;
        unsigned char* dst = lds + wave * 4096;
#pragma unroll
        for (int i = 0; i < 4; ++i)
            gload_lds16(src + i * 1024, dst + i * 1024);
    }

    // Per-slot running minima. Slot (tt, r): code = j*16 + q*4 + r,
    // j = chunk*8 + sub in [0,64) -> mj byte-packed (4 x 8-bit) per tt.
    float    md[4][4];
    unsigned mjp[4];
#pragma unroll
    for (int tt = 0; tt < 4; ++tt) {
        mjp[tt] = 0u;
#pragma unroll
        for (int r = 0; r < 4; ++r) md[tt][r] = INFINITY;
    }

    for (int chunk = 0; chunk < 8; ++chunk) {
        __syncthreads();   // drains this chunk's async loads (+hcnS on iter 0)

        if (chunk < 7) {   // prefetch next chunk into the other buffer
            const unsigned char* src =
                cbS_k + (size_t)(chunk + 1) * 16384 + wave * 4096 + lane * 16;
            unsigned char* dst = lds + ((chunk + 1) & 1) * LDSBUF + wave * 4096;
#pragma unroll
            for (int i = 0; i < 4; ++i)
                gload_lds16(src + i * 1024, dst + i * 1024);
        }

        const unsigned char* buf = lds + (chunk & 1) * LDSBUF;
#pragma unroll
        for (int sub = 0; sub < 8; ++sub) {
            const unsigned char* rowb = buf + (sub * 16 + ln) * 128;
            f32x4 h4 = *(const f32x4*)(hcnS + chunk * 128 + sub * 16 + q4);
            f32x4 a[4];
#pragma unroll
            for (int tt = 0; tt < 4; ++tt) a[tt] = h4;
#pragma unroll
            for (int ks = 0; ks < 2; ++ks) {
                int cidx = ((ks * 4 + q) ^ (ln & 7)) * 16;
                bf16x8 ah = __builtin_bit_cast(bf16x8, *(const short8*)(rowb + cidx));
#pragma unroll
                for (int tt = 0; tt < 4; ++tt)
                    a[tt] = __builtin_amdgcn_mfma_f32_16x16x32_bf16(
                        ah, __builtin_bit_cast(bf16x8, bh[tt][ks]), a[tt], 0, 0, 0);
            }
            const unsigned j = (unsigned)(chunk * 8 + sub);
#pragma unroll
            for (int tt = 0; tt < 4; ++tt) {
#pragma unroll
                for (int r = 0; r < 4; ++r) {
                    bool lt = a[tt][r] < md[tt][r];
                    md[tt][r] = lt ? a[tt][r] : md[tt][r];
                    unsigned upd = (mjp[tt] & ~(0xFFu << (8 * r))) | (j << (8 * r));
                    mjp[tt] = lt ? upd : mjp[tt];
                }
            }
        }
    }

    // ---- Epilogue A: top-1 consensus + SSE + counts + idx publish ----
    double waveSse = 0.0;

#pragma unroll
    for (int tt = 0; tt < 4; ++tt) {
        // Fold 4 slots -> in-lane top-1, lexicographic (value, code).
        float d1 = md[tt][0];
        int   c1 = (int)(mjp[tt] & 0xFFu) * 16 + q4;
#pragma unroll
        for (int r = 1; r < 4; ++r) {
            float v  = md[tt][r];
            int   cv = (int)((mjp[tt] >> (8 * r)) & 0xFFu) * 16 + q4 + r;
            bool w = (v < d1) || (v == d1 && cv < c1);
            d1 = w ? v : d1;
            c1 = w ? cv : c1;
        }
        // Cross-lane top-1 merge over q (xor 16, 32), lexicographic ->
        // all 4 q-lanes converge bitwise on the same (d1, c1).
#pragma unroll
        for (int off = 16; off <= 32; off <<= 1) {
            float ov = __shfl_xor(d1, off);
            int   oc = __shfl_xor(c1, off);
            bool w = (ov < d1) || (ov == d1 && oc < c1);
            d1 = w ? ov : d1;
            c1 = w ? oc : c1;
        }

        if (q == 0) {                        // one vote per query
            // ||x - c||^2 = ||x||^2 + 2*(0.5||c||^2 - x.c) = xn + 2*score
            waveSse += (double)(xn[tt] + 2.0f * d1);
            atomicAdd(&counts[k * C_ + c1], 1);
            idxS[wave * 64 + tt * 16 + ln] = c1;   // idxS[i] = idx for t0b+i
        }
    }

    // One fp64 atomic per wave.
    for (int off = 32; off > 0; off >>= 1) waveSse += __shfl_down(waveSse, off);
    if (lane == 0) atomicAdd(sse, waveSse);

    __syncthreads();   // idx table visible to all waves

    // ---- Epilogue B: coalesced quantized write (R2-proven pattern) ----
    // Wave owns 16 ch rows (ch = wave*16 + h*4 + rr) x 256 t. Lane l covers
    // t = t0b + 4l..4l+3: gather the 4 selected codebook row-slices as exact
    // fp32 f32x4 (L2-hot), register-transpose, dwordx4 stores (64 lanes x
    // 16 B = 1 KB contiguous per wave-instr -> full cache lines, no RMW).
    const float* cb_k = cb + (size_t)k * C_ * CH_;
    i32x4 idx4 = *(const i32x4*)(idxS + 4 * lane);
#pragma unroll
    for (int h = 0; h < 4; ++h) {
        f32x4 g[4];
#pragma unroll
        for (int m = 0; m < 4; ++m)
            g[m] = *(const f32x4*)(cb_k + (size_t)idx4[m] * CH_
                                   + wave * 16 + h * 4);
#pragma unroll
        for (int rr = 0; rr < 4; ++rr) {
            f32x4 v = { g[0][rr], g[1][rr], g[2][rr], g[3][rr] };
            *(f32x4*)(out + ((size_t)(b * D_ + k * CH_ + wave * 16 + h * 4
                                      + rr)) * T_ + t0b + 4 * lane) = v;
        }
    }
}

// ---------------------------------------------------------------------------
// Finalize: one block per k -> perplexity; block 0 also writes commit loss.
// ---------------------------------------------------------------------------
__global__ void vq_final(const int* __restrict__ counts,
                         const double* __restrict__ sse,
                         float* __restrict__ out) {
    __shared__ double part[4];
    const int tid = threadIdx.x;
    const int k   = blockIdx.x;
    double local = 0.0;
    for (int j = tid; j < C_; j += 256) {
        double p = (double)counts[k * C_ + j] * (1.0 / (double)(B_ * T_));
        local += -p * log(p + 1e-8);
    }
    for (int off = 32; off > 0; off >>= 1) local += __shfl_down(local, off);
    if ((tid & 63) == 0) part[tid >> 6] = local;
    __syncthreads();
    if (tid == 0) {
        double sum = part[0] + part[1] + part[2] + part[3];
        out[QOFF + 1 + k] = (float)exp(sum);
        if (k == 0)
            out[QOFF] = (float)(1.25 * (*sse) / (double)NEL_);
    }
}

// ---------------------------------------------------------------------------
extern "C" void kernel_launch(void* const* d_in, const int* in_sizes, int n_in,
                              void* d_out, int out_size, void* d_ws, size_t ws_size,
                              hipStream_t stream) {
    const float* x  = (const float*)d_in[0];
    const float* cb = (const float*)d_in[1];
    float* out = (float*)d_out;

    float*         hcn    = (float*)((char*)d_ws + WS_HCN);
    int*           counts = (int*)((char*)d_ws + WS_CNT);
    double*        sse    = (double*)((char*)d_ws + WS_SSE);
    unsigned char* cbS    = (unsigned char*)((char*)d_ws + WS_CBS);

    vq_prep<<<(K_ * C_ * 8) / 256, 256, 0, stream>>>(cb, cbS, hcn, counts, sse);
    vq_main<<<B_ * K_ * (T_ / 256), 256, 0, stream>>>(x, cb, cbS, hcn,
                                                      out, counts, sse);
    vq_final<<<K_, 256, 0, stream>>>(counts, sse, out);
}

// Round 9
// 198.192 us; speedup vs baseline: 1.2482x; 1.0315x over previous
//
#include <hip/hip_runtime.h>
#include <hip/hip_bf16.h>
#include <math.h>

// Problem constants
#define B_   16
#define D_   512
#define T_   2048
#define K_   8
#define C_   1024
#define CH_  64
#define NEL_ (B_ * D_ * T_)        // 16777216
#define QOFF 16777216              // out: [quantized | commit | ppl[8]]

// ws layout
#define WS_HCN   0                          // float[K*C]   32 KB (0.5*||c||^2)
#define WS_CNT   32768                      // int[K*C]     32 KB
#define WS_SSE   65536                      // double       8 B
#define WS_CBS   66048                      // swizzled bf16 (hi only) image, 8192 rows * 128 B = 1 MB
// image: row r (= k*1024+c) at WS_CBS + r*128; 16B group s (s=0..7, ch 8s..8s+7,
// negated bf16) stored at ((s ^ (r & 7)) * 16).

typedef __attribute__((ext_vector_type(8))) short   short8;
typedef __attribute__((ext_vector_type(8))) __bf16  bf16x8;
typedef __attribute__((ext_vector_type(4))) float   f32x4;
typedef __attribute__((ext_vector_type(4))) int     i32x4;

__device__ __forceinline__ unsigned short f2bf_rne(float f) {
    unsigned u = __builtin_bit_cast(unsigned, f);
    u = u + 0x7FFFu + ((u >> 16) & 1u);
    return (unsigned short)(u >> 16);
}

__device__ __forceinline__ void gload_lds16(const void* gsrc, void* ldst) {
    __builtin_amdgcn_global_load_lds(
        (const __attribute__((address_space(1))) unsigned int*)gsrc,
        (__attribute__((address_space(3))) unsigned int*)ldst,
        16, 0, 0);
}

// ---------------------------------------------------------------------------
// Prep (R0/R2-proven): swizzled bf16 (hi-only) image of (-c) + 0.5*||c||^2,
// plus counts/sse zero-init. One thread per 16B group. 65536 threads.
// ---------------------------------------------------------------------------
__global__ void vq_prep(const float* __restrict__ cb,
                        unsigned char* __restrict__ cbS,
                        float* __restrict__ hcn,
                        int* __restrict__ counts,
                        double* __restrict__ sse) {
    int g   = blockIdx.x * 256 + threadIdx.x;
    if (g < K_ * C_) counts[g] = 0;
    if (g == 0) *sse = 0.0;

    int row = g >> 3;
    int s8  = g & 7;
    const float* src = cb + (size_t)row * CH_;

    short8 val;
#pragma unroll
    for (int j = 0; j < 8; ++j)
        val[j] = (short)f2bf_rne(-src[s8 * 8 + j]);
    *(short8*)(cbS + (size_t)row * 128 + ((s8 ^ (row & 7)) * 16)) = val;

    if (s8 == 0) {
        float s = 0.f;
#pragma unroll 8
        for (int ch = 0; ch < CH_; ++ch) {
            float v = src[ch];
            s = fmaf(v, v, s);
        }
        hcn[row] = 0.5f * s;
    }
}

// ---------------------------------------------------------------------------
// Main — R7 chassis (passed, 117 µs) with ONE change: slim argmin tracker.
//
// R8 POST-MORTEM (important): the bit-packed fminf argmin (code in low
// mantissa bits) failed 5/5 times across R3-R6/R8 with a ppl=exp(0)
// signature while commit (min-VALUE path) passed — the injected code bits
// come out constant (likely fast-math folding of fminf chains seeded from
// INFINITY). RULE: no bit-packed fminf argmin on this toolchain. Explicit
// compare-select (a < md) is proven (R0/R1/R2/R7 all passed with it).
//
// R7 post-mortem: VALUBusy 38% (~45 µs) dominated; the 4-slot tracker was
// ~20 VALU/tt/sub. New tracker: min-tree + equality r-extract + strict-<
// update = ~12 VALU/tt/sub and 8 regs of state vs 20. Selection semantics
// BIT-IDENTICAL to R7: min-tree + first-match r picks smallest r on ties,
// strict < keeps earliest j; code order (j*16 dominates r) => same
// lexicographic winner as R7's per-slot + end-fold. absmax must reproduce
// 0.6113281 exactly.
//
// Block = 256 (4 waves), wave owns 64 t (4 t-tiles) of one (b,k).
// Grid = 1024 = 4 blocks/CU. LDS 37888 B (R7-proven).
// Staging: swizzled hi-only image, global_load_lds 16B, 128-code chunks,
// double buffer, 8 drains/block (R0-proven).
// Epilogue: idxS publish + coalesced full-line dwordx4 out-writes (R7-proven).
// ---------------------------------------------------------------------------
#define LDSBUF 16384

__global__ __launch_bounds__(256, 2) void vq_main(
    const float* __restrict__ x,
    const float* __restrict__ cb,
    const unsigned char* __restrict__ cbS,
    const float* __restrict__ hcn,
    float* __restrict__ out,
    int* __restrict__ counts,
    double* __restrict__ sse)
{
    __shared__ __align__(16) unsigned char lds[2 * LDSBUF + 4096 + 1024];
    float* hcnS = (float*)(lds + 2 * LDSBUF);
    int*   idxS = (int*)(lds + 2 * LDSBUF + 4096);

    const int tid  = threadIdx.x;
    const int lane = tid & 63;
    const int wave = tid >> 6;          // 0..3
    const int ln   = lane & 15;
    const int q    = lane >> 4;
    const int q4   = q * 4;

    const int bid = blockIdx.x;
    const int tc  = bid & 7;            // 8 t-chunks of 256
    const int k   = (bid >> 3) & 7;
    const int b   = bid >> 6;
    const int t0b = tc * 256;           // block's t base
    const int tw  = t0b + wave * 64;    // wave's t base

    // ---- B fragments (queries) + ||x||^2 per query (R0 verbatim) ----
    short8 bh[4][2];    // [tt][kstep]
    float  xn[4];       // ||x_t||^2 for t = tw + tt*16 + ln (all lanes)
#pragma unroll
    for (int tt = 0; tt < 4; ++tt) {
        int t = tw + tt * 16 + ln;
        float pn = 0.f;
#pragma unroll
        for (int ks = 0; ks < 2; ++ks) {
            const float* xp = x + ((size_t)(b * D_ + k * CH_ + ks * 32 + q * 8)) * T_ + t;
            short8 sh;
#pragma unroll
            for (int j = 0; j < 8; ++j) {
                float v = xp[(size_t)j * T_];
                pn = fmaf(v, v, pn);
                sh[j] = (short)f2bf_rne(v);
            }
            bh[tt][ks] = sh;
        }
        pn += __shfl_xor(pn, 16);       // sum the 4 q-lane partials
        pn += __shfl_xor(pn, 32);
        xn[tt] = pn;
    }

    const unsigned char* cbS_k = cbS + (size_t)k * C_ * 128;
    const float*         hcn_k = hcn + k * C_;

    // Stage hcn (4 KB) once via plain LDS writes (visible at first barrier).
    for (int i = tid; i < C_; i += 256) hcnS[i] = hcn_k[i];

    // Stage chunk 0 (128 codes, 16 KB) into buf0: each wave 4 x 1 KB async.
    {
        const unsigned char* src = cbS_k + wave * 4096 + lane * 16;
        unsigned char* dst = lds + wave * 4096;
#pragma unroll
        for (int i = 0; i < 4; ++i)
            gload_lds16(src + i * 1024, dst + i * 1024);
    }

    // Slim tracker: one (value, packed j*4+r) pair per t-tile.
    // Candidate slot (tt, r) at (chunk, sub): j = chunk*8+sub in [0,64),
    // code = j*16 + q4 + r. mc stores j*4 + r (decoded in the epilogue).
    float md[4];
    int   mc[4];
#pragma unroll
    for (int tt = 0; tt < 4; ++tt) { md[tt] = INFINITY; mc[tt] = 0; }

    for (int chunk = 0; chunk < 8; ++chunk) {
        __syncthreads();   // drains this chunk's async loads (+hcnS on iter 0)

        if (chunk < 7) {   // prefetch next chunk into the other buffer
            const unsigned char* src =
                cbS_k + (size_t)(chunk + 1) * 16384 + wave * 4096 + lane * 16;
            unsigned char* dst = lds + ((chunk + 1) & 1) * LDSBUF + wave * 4096;
#pragma unroll
            for (int i = 0; i < 4; ++i)
                gload_lds16(src + i * 1024, dst + i * 1024);
        }

        const unsigned char* buf = lds + (chunk & 1) * LDSBUF;
#pragma unroll
        for (int sub = 0; sub < 8; ++sub) {
            const unsigned char* rowb = buf + (sub * 16 + ln) * 128;
            f32x4 h4 = *(const f32x4*)(hcnS + chunk * 128 + sub * 16 + q4);
            f32x4 a[4];
#pragma unroll
            for (int tt = 0; tt < 4; ++tt) a[tt] = h4;
#pragma unroll
            for (int ks = 0; ks < 2; ++ks) {
                int cidx = ((ks * 4 + q) ^ (ln & 7)) * 16;
                bf16x8 ah = __builtin_bit_cast(bf16x8, *(const short8*)(rowb + cidx));
#pragma unroll
                for (int tt = 0; tt < 4; ++tt)
                    a[tt] = __builtin_amdgcn_mfma_f32_16x16x32_bf16(
                        ah, __builtin_bit_cast(bf16x8, bh[tt][ks]), a[tt], 0, 0, 0);
            }
            const int j4 = (chunk * 8 + sub) * 4;
#pragma unroll
            for (int tt = 0; tt < 4; ++tt) {
                // Min-tree over the 4 r-slots, then first-match r extraction
                // (smallest r on ties — matches reference first-occurrence).
                float m01 = fminf(a[tt][0], a[tt][1]);
                float m23 = fminf(a[tt][2], a[tt][3]);
                float m   = fminf(m01, m23);
                int rw = (m == a[tt][0]) ? 0 :
                         (m == a[tt][1]) ? 1 :
                         (m == a[tt][2]) ? 2 : 3;
                bool lt = m < md[tt];      // strict < keeps earliest j on ties
                md[tt] = lt ? m : md[tt];
                mc[tt] = lt ? (j4 + rw) : mc[tt];
            }
        }
    }

    // ---- Epilogue A: top-1 consensus + SSE + counts + idx publish ----
    double waveSse = 0.0;

#pragma unroll
    for (int tt = 0; tt < 4; ++tt) {
        float d1 = md[tt];
        int   c1 = ((mc[tt] >> 2) << 4) + q4 + (mc[tt] & 3);   // j*16 + q4 + r
        // Cross-lane top-1 merge over q (xor 16, 32), lexicographic ->
        // all 4 q-lanes converge bitwise on the same (d1, c1). (R7-proven.)
#pragma unroll
        for (int off = 16; off <= 32; off <<= 1) {
            float ov = __shfl_xor(d1, off);
            int   oc = __shfl_xor(c1, off);
            bool w = (ov < d1) || (ov == d1 && oc < c1);
            d1 = w ? ov : d1;
            c1 = w ? oc : c1;
        }

        if (q == 0) {                        // one vote per query
            // ||x - c||^2 = ||x||^2 + 2*(0.5||c||^2 - x.c) = xn + 2*score
            waveSse += (double)(xn[tt] + 2.0f * d1);
            atomicAdd(&counts[k * C_ + c1], 1);
            idxS[wave * 64 + tt * 16 + ln] = c1;   // idxS[i] = idx for t0b+i
        }
    }

    // One fp64 atomic per wave.
    for (int off = 32; off > 0; off >>= 1) waveSse += __shfl_down(waveSse, off);
    if (lane == 0) atomicAdd(sse, waveSse);

    __syncthreads();   // idx table visible to all waves

    // ---- Epilogue B: coalesced quantized write (R7-proven) ----
    // Wave owns 16 ch rows (ch = wave*16 + h*4 + rr) x 256 t. Lane l covers
    // t = t0b + 4l..4l+3: gather the 4 selected codebook row-slices as exact
    // fp32 f32x4 (L2-hot), register-transpose, dwordx4 stores (64 lanes x
    // 16 B = 1 KB contiguous per wave-instr -> full cache lines, no RMW).
    const float* cb_k = cb + (size_t)k * C_ * CH_;
    i32x4 idx4 = *(const i32x4*)(idxS + 4 * lane);
#pragma unroll
    for (int h = 0; h < 4; ++h) {
        f32x4 g[4];
#pragma unroll
        for (int m = 0; m < 4; ++m)
            g[m] = *(const f32x4*)(cb_k + (size_t)idx4[m] * CH_
                                   + wave * 16 + h * 4);
#pragma unroll
        for (int rr = 0; rr < 4; ++rr) {
            f32x4 v = { g[0][rr], g[1][rr], g[2][rr], g[3][rr] };
            *(f32x4*)(out + ((size_t)(b * D_ + k * CH_ + wave * 16 + h * 4
                                      + rr)) * T_ + t0b + 4 * lane) = v;
        }
    }
}

// ---------------------------------------------------------------------------
// Finalize: one block per k -> perplexity; block 0 also writes commit loss.
// ---------------------------------------------------------------------------
__global__ void vq_final(const int* __restrict__ counts,
                         const double* __restrict__ sse,
                         float* __restrict__ out) {
    __shared__ double part[4];
    const int tid = threadIdx.x;
    const int k   = blockIdx.x;
    double local = 0.0;
    for (int j = tid; j < C_; j += 256) {
        double p = (double)counts[k * C_ + j] * (1.0 / (double)(B_ * T_));
        local += -p * log(p + 1e-8);
    }
    for (int off = 32; off > 0; off >>= 1) local += __shfl_down(local, off);
    if ((tid & 63) == 0) part[tid >> 6] = local;
    __syncthreads();
    if (tid == 0) {
        double sum = part[0] + part[1] + part[2] + part[3];
        out[QOFF + 1 + k] = (float)exp(sum);
        if (k == 0)
            out[QOFF] = (float)(1.25 * (*sse) / (double)NEL_);
    }
}

// ---------------------------------------------------------------------------
extern "C" void kernel_launch(void* const* d_in, const int* in_sizes, int n_in,
                              void* d_out, int out_size, void* d_ws, size_t ws_size,
                              hipStream_t stream) {
    const float* x  = (const float*)d_in[0];
    const float* cb = (const float*)d_in[1];
    float* out = (float*)d_out;

    float*         hcn    = (float*)((char*)d_ws + WS_HCN);
    int*           counts = (int*)((char*)d_ws + WS_CNT);
    double*        sse    = (double*)((char*)d_ws + WS_SSE);
    unsigned char* cbS    = (unsigned char*)((char*)d_ws + WS_CBS);

    vq_prep<<<(K_ * C_ * 8) / 256, 256, 0, stream>>>(cb, cbS, hcn, counts, sse);
    vq_main<<<B_ * K_ * (T_ / 256), 256, 0, stream>>>(x, cb, cbS, hcn,
                                                      out, counts, sse);
    vq_final<<<K_, 256, 0, stream>>>(counts, sse, out);
}